// Round 5
// baseline (323.978 us; speedup 1.0000x reference)
//
#include <hip/hip_runtime.h>
#include <math.h>

#define N_NODES 50000
#define E_EDGES 800000
#define IN_DIM  256
#define D_DIM   96
#define OUT_DIM 128

typedef __attribute__((ext_vector_type(8))) short short8;
typedef __attribute__((ext_vector_type(4))) float f32x4;

__device__ __forceinline__ unsigned short f2bf(float f) {
    unsigned u = __float_as_uint(f);
    unsigned r = u + 0x7fffu + ((u >> 16) & 1u);
    return (unsigned short)(r >> 16);
}
__device__ __forceinline__ float bf2f(unsigned short u) {
    return __uint_as_float(((unsigned)u) << 16);
}
__device__ __forceinline__ float sigm(float x) { return 1.f / (1.f + __expf(-x)); }
__device__ __forceinline__ float ftanh(float x) { return 1.f - 2.f / (1.f + __expf(2.f * x)); }

// pack 8 consecutive f32 -> short8 of bf16 (round-to-nearest-even-ish)
__device__ __forceinline__ short8 pack8(const float* __restrict__ p) {
    float4 v0 = *(const float4*)p;
    float4 v1 = *(const float4*)(p + 4);
    union { short8 s; unsigned u[4]; } r;
    r.u[0] = (unsigned)f2bf(v0.x) | ((unsigned)f2bf(v0.y) << 16);
    r.u[1] = (unsigned)f2bf(v0.z) | ((unsigned)f2bf(v0.w) << 16);
    r.u[2] = (unsigned)f2bf(v1.x) | ((unsigned)f2bf(v1.y) << 16);
    r.u[3] = (unsigned)f2bf(v1.z) | ((unsigned)f2bf(v1.w) << 16);
    return r.s;
}

// ---------- K1: feat = x @ W_fc  ([N,256]@[256,96] -> bf16 [N,96]) ----------
__global__ __launch_bounds__(192)
void k_featmm(const float* __restrict__ x, const float* __restrict__ Wfc,
              unsigned short* __restrict__ feat) {
    __shared__ float xs[64][68];
    const int t    = threadIdx.x;
    const int j    = t % 96;
    const int half = t / 96;
    const int n0   = blockIdx.x * 64;
    const int bn   = half * 32;

    float acc[32];
#pragma unroll
    for (int i = 0; i < 32; ++i) acc[i] = 0.f;

    for (int k0 = 0; k0 < IN_DIM; k0 += 64) {
        __syncthreads();
        for (int idx = t; idx < 64 * 64; idx += 192) {
            int nl = idx >> 6, kk = idx & 63;
            int n = n0 + nl;
            xs[kk][nl] = (n < N_NODES) ? x[n * IN_DIM + k0 + kk] : 0.f;
        }
        __syncthreads();
#pragma unroll 4
        for (int kk = 0; kk < 64; ++kk) {
            float w = Wfc[(k0 + kk) * D_DIM + j];
            const float4* row = (const float4*)&xs[kk][bn];
#pragma unroll
            for (int q = 0; q < 8; ++q) {
                float4 v = row[q];
                acc[4*q+0] += w * v.x; acc[4*q+1] += w * v.y;
                acc[4*q+2] += w * v.z; acc[4*q+3] += w * v.w;
            }
        }
    }
#pragma unroll
    for (int i = 0; i < 32; ++i) {
        int n = n0 + bn + i;
        if (n < N_NODES) feat[n * D_DIM + j] = f2bf(acc[i]);
    }
}

// ---------- K2: el/er per node (bf16 feat) ----------
__global__ __launch_bounds__(256)
void k_node_attn(const unsigned short* __restrict__ feat,
                 const float* __restrict__ al, const float* __restrict__ ar,
                 float* __restrict__ el, float* __restrict__ er) {
    int n = blockIdx.x * blockDim.x + threadIdx.x;
    if (n >= N_NODES) return;
    const uint4* f4 = (const uint4*)(feat + n * D_DIM);   // 12 × 8 bf16
    float sl = 0.f, sr = 0.f;
#pragma unroll
    for (int q = 0; q < 12; ++q) {
        uint4 v = f4[q];
        unsigned uu[4] = {v.x, v.y, v.z, v.w};
#pragma unroll
        for (int p = 0; p < 4; ++p) {
            float f0 = bf2f((unsigned short)(uu[p] & 0xffffu));
            float f1 = bf2f((unsigned short)(uu[p] >> 16));
            int k = q * 8 + p * 2;
            sl += f0 * al[k] + f1 * al[k + 1];
            sr += f0 * ar[k] + f1 * ar[k + 1];
        }
    }
    el[n] = sl; er[n] = sr;
}

// ---------- K3a: histogram of dst ----------
__global__ __launch_bounds__(256)
void k_hist(const int* __restrict__ dst, int* __restrict__ cnt) {
    int e = blockIdx.x * blockDim.x + threadIdx.x;
    if (e >= E_EDGES) return;
    atomicAdd(&cnt[dst[e]], 1);
}

// ---------- K3b: wave-parallel range allocator (order-free "scan") ----------
__global__ __launch_bounds__(256)
void k_alloc(const int* __restrict__ cnt, int* __restrict__ start,
             int* __restrict__ cursor, int* __restrict__ total) {
    const int n    = blockIdx.x * 256 + threadIdx.x;
    const int lane = threadIdx.x & 63;
    int c = (n < N_NODES) ? cnt[n] : 0;
    int incl = c;
#pragma unroll
    for (int d = 1; d < 64; d <<= 1) {
        int v = __shfl_up(incl, d, 64);
        if (lane >= d) incl += v;
    }
    int wsum = __shfl(incl, 63, 64);
    int base = 0;
    if (lane == 63) base = atomicAdd(total, wsum);
    base = __shfl(base, 63, 64);
    if (n < N_NODES) {
        int s = base + incl - c;
        start[n] = s;
        cursor[n] = s;
    }
}

// ---------- K3c: bucket src-ids by dst ----------
__global__ __launch_bounds__(256)
void k_bucket(const int* __restrict__ src, const int* __restrict__ dst,
              int* __restrict__ cursor, int* __restrict__ ebuf_src) {
    int e = blockIdx.x * blockDim.x + threadIdx.x;
    if (e >= E_EDGES) return;
    int pos = atomicAdd(&cursor[dst[e]], 1);
    ebuf_src[pos] = src[e];
}

// ---------- K3d: softmax-gather -> xmid bf16 [N,96] ----------
__global__ __launch_bounds__(256)
void k_gather(const int* __restrict__ start, const int* __restrict__ cnt,
              const int* __restrict__ ebuf_src,
              const float* __restrict__ el, const float* __restrict__ er,
              const unsigned short* __restrict__ feat, const float* __restrict__ bias,
              unsigned short* __restrict__ xmid) {
    const int n    = (blockIdx.x * 256 + threadIdx.x) >> 5;
    const int lane = threadIdx.x & 31;
    if (n >= N_NODES) return;
    const int o0 = start[n];
    const int deg = cnt[n];
    const float ern = er[n];

    float vmax = -INFINITY;
    for (int i = lane; i < deg; i += 32) {
        int s = ebuf_src[o0 + i];
        float v = el[s] + ern; v = v > 0.f ? v : 0.2f * v;
        vmax = fmaxf(vmax, v);
    }
#pragma unroll
    for (int d = 16; d; d >>= 1) vmax = fmaxf(vmax, __shfl_xor(vmax, d, 32));

    float ssum = 0.f;
    for (int i = lane; i < deg; i += 32) {
        int s = ebuf_src[o0 + i];
        float v = el[s] + ern; v = v > 0.f ? v : 0.2f * v;
        ssum += __expf(v - vmax);
    }
#pragma unroll
    for (int d = 16; d; d >>= 1) ssum += __shfl_xor(ssum, d, 32);

    const float inv = 1.f / (ssum > 0.f ? ssum : 1.f);

    float a0 = 0.f, a1 = 0.f, a2 = 0.f;
    for (int i = 0; i < deg; ++i) {
        int s = ebuf_src[o0 + i];
        float v = el[s] + ern; v = v > 0.f ? v : 0.2f * v;
        float w = __expf(v - vmax);
        const unsigned short* fr = feat + s * D_DIM;
        a0 += w * bf2f(fr[lane]);
        a1 += w * bf2f(fr[lane + 32]);
        a2 += w * bf2f(fr[lane + 64]);
    }
    unsigned short* zr = xmid + (size_t)n * D_DIM;
    zr[lane]      = f2bf(ftanh(a0 * inv + bias[lane]));
    zr[lane + 32] = f2bf(ftanh(a1 * inv + bias[lane + 32]));
    zr[lane + 64] = f2bf(ftanh(a2 * inv + bias[lane + 64]));
}

// ---------- prep: W -> fragment-major packed bf16 + bsum ----------
// Wb_frag[((cf*7+ks)*64+l)*8+j] = W[k][col], k=ks*32+(l>>4)*8+j, col=cf*16+(l&15)
__global__ __launch_bounds__(256)
void k_prep_w(const float* __restrict__ W_ih, const float* __restrict__ W_hh,
              const float* __restrict__ b_ih, const float* __restrict__ b_hh,
              unsigned short* __restrict__ Wb_frag, float* __restrict__ bsum) {
    int tid = blockIdx.x * 256 + threadIdx.x;
    if (tid < 512) bsum[tid] = b_ih[tid] + b_hh[tid];
    if (tid >= 32 * 7 * 64 * 8) return;
    int j = tid & 7;
    int rest = tid >> 3;
    int l = rest & 63;
    int rest2 = rest >> 6;
    int ks = rest2 % 7;
    int cf = rest2 / 7;
    int k   = ks * 32 + (l >> 4) * 8 + j;
    int col = cf * 16 + (l & 15);
    float v = (k < 96) ? W_ih[col * 96 + k] : W_hh[col * 128 + (k - 96)];
    Wb_frag[tid] = f2bf(v);
}

// ---------- K4: MFMA gates GEMM + LSTM pointwise; LDS-staged coalesced stores ----------
// Block: 4 waves, 32 rows. Wave w: cols w*32 + {0,16}, gate stride 128.
__global__ __launch_bounds__(256)
void k_lstm_mfma(const unsigned short* __restrict__ xmid,   // [N,96] bf16
                 const float* __restrict__ h0,              // [N,128] f32
                 const unsigned short* __restrict__ Wb_frag,
                 const float* __restrict__ bsum,
                 const float* __restrict__ cin0,
                 float* __restrict__ out_h1a, float* __restrict__ out_h1b,
                 float* __restrict__ out_c1) {
    __shared__ float h1s[32][132];     // pad 132: 2-way max on write, free
    __shared__ float c1s[32][132];
    const int t     = threadIdx.x;
    const int lane  = t & 63;
    const int w     = t >> 6;
    const int wc0   = w * 32;
    const int n0    = blockIdx.x * 32;
    const int rfrag = lane & 15;
    const int khalf = lane >> 4;

    const int r0 = min(n0 + rfrag,      N_NODES - 1);   // clamped A rows (tail block)
    const int r1 = min(n0 + 16 + rfrag, N_NODES - 1);

    f32x4 acc[2][2][4];
#pragma unroll
    for (int m = 0; m < 2; ++m)
#pragma unroll
        for (int cc = 0; cc < 2; ++cc)
#pragma unroll
            for (int g = 0; g < 4; ++g)
                acc[m][cc][g] = (f32x4){0.f, 0.f, 0.f, 0.f};

#pragma unroll
    for (int ks = 0; ks < 7; ++ks) {
        short8 a0, a1;
        if (ks < 3) {            // xmid cols [0,96) — already bf16
            a0 = *(const short8*)(xmid + (size_t)r0 * D_DIM + ks * 32 + khalf * 8);
            a1 = *(const short8*)(xmid + (size_t)r1 * D_DIM + ks * 32 + khalf * 8);
        } else {                 // h0 cols [0,128) — convert f32->bf16 in-register
            a0 = pack8(h0 + (size_t)r0 * OUT_DIM + (ks - 3) * 32 + khalf * 8);
            a1 = pack8(h0 + (size_t)r1 * OUT_DIM + (ks - 3) * 32 + khalf * 8);
        }
#pragma unroll
        for (int g = 0; g < 4; ++g) {
#pragma unroll
            for (int cc = 0; cc < 2; ++cc) {
                int cf = w * 2 + cc + 8 * g;
                short8 b = *(const short8*)(Wb_frag + (size_t)((cf * 7 + ks) * 64 + lane) * 8);
                acc[0][cc][g] = __builtin_amdgcn_mfma_f32_16x16x32_bf16(a0, b, acc[0][cc][g], 0, 0, 0);
                acc[1][cc][g] = __builtin_amdgcn_mfma_f32_16x16x32_bf16(a1, b, acc[1][cc][g], 0, 0, 0);
            }
        }
    }

    // epilogue: per-lane LSTM pointwise -> LDS tile
#pragma unroll
    for (int m = 0; m < 2; ++m) {
#pragma unroll
        for (int cc = 0; cc < 2; ++cc) {
            const int col = wc0 + cc * 16 + rfrag;
            const float bi = bsum[col];
            const float bf = bsum[col + 128];
            const float bg = bsum[col + 256];
            const float bo = bsum[col + 384];
#pragma unroll
            for (int reg = 0; reg < 4; ++reg) {
                const int rl = m * 16 + khalf * 4 + reg;       // local row
                const int r  = min(n0 + rl, N_NODES - 1);      // clamped c0 read
                float iv = acc[m][cc][0][reg] + bi;
                float fv = acc[m][cc][1][reg] + bf;
                float gv = acc[m][cc][2][reg] + bg;
                float ov = acc[m][cc][3][reg] + bo;
                float c1 = sigm(fv) * cin0[(size_t)r * OUT_DIM + col] + sigm(iv) * ftanh(gv);
                float h1 = sigm(ov) * ftanh(c1);
                h1s[rl][col] = h1;
                c1s[rl][col] = c1;
            }
        }
    }
    __syncthreads();

    // coalesced full-line stores: 32 rows x 128 cols, float4 per thread
#pragma unroll
    for (int it = 0; it < 4; ++it) {
        int idx = it * 256 + t;
        int row = idx >> 5;
        int c4  = (idx & 31) * 4;
        int gr  = n0 + row;
        if (gr < N_NODES) {
            float4 h = *(float4*)&h1s[row][c4];
            float4 c = *(float4*)&c1s[row][c4];
            *(float4*)(out_h1a + (size_t)gr * OUT_DIM + c4) = h;
            *(float4*)(out_h1b + (size_t)gr * OUT_DIM + c4) = h;
            *(float4*)(out_c1  + (size_t)gr * OUT_DIM + c4) = c;
        }
    }
}

extern "C" void kernel_launch(void* const* d_in, const int* in_sizes, int n_in,
                              void* d_out, int out_size, void* d_ws, size_t ws_size,
                              hipStream_t stream) {
    const float* x      = (const float*)d_in[0];
    const float* W_fc   = (const float*)d_in[1];
    const float* attn_l = (const float*)d_in[2];
    const float* attn_r = (const float*)d_in[3];
    const float* bias   = (const float*)d_in[4];
    const float* W_ih   = (const float*)d_in[5];
    const float* W_hh   = (const float*)d_in[6];
    const float* b_ih   = (const float*)d_in[7];
    const float* b_hh   = (const float*)d_in[8];
    const float* h0     = (const float*)d_in[9];
    const float* c0     = (const float*)d_in[10];
    const int*   src    = (const int*)d_in[11];
    const int*   dst    = (const int*)d_in[12];
    float* out = (float*)d_out;

    char* base = (char*)d_ws;
    unsigned short* feat    = (unsigned short*)(base);               //  9,600,000 B
    unsigned short* xmid    = (unsigned short*)(base + 9600000);     //  9,600,000 B
    float*          el      = (float*)(base + 19200000);             //  200,000
    float*          er      = (float*)(base + 19400000);             //  200,000
    int*            cnt     = (int*)(base + 19600000);               //  200,000
    int*            total   = (int*)(base + 19800000);               //  4
    int*            startv  = (int*)(base + 19800004);               //  200,000
    int*            cursor  = (int*)(base + 20000004);               //  200,000
    int*            ebuf    = (int*)(base + 20200004);               //  3,200,000
    unsigned short* Wb_frag = (unsigned short*)(base + 23400016);    //  229,376 (16B aligned)
    float*          bsum    = (float*)(base + 23629392);             //  2,048

    // zero cnt + total in one memset (contiguous)
    hipMemsetAsync(cnt, 0, (size_t)N_NODES * sizeof(int) + sizeof(int), stream);

    k_prep_w <<<(32 * 7 * 64 * 8 + 255) / 256, 256, 0, stream>>>(W_ih, W_hh, b_ih, b_hh,
                                                                 Wb_frag, bsum);

    k_featmm<<<(N_NODES + 63) / 64, 192, 0, stream>>>(x, W_fc, feat);
    k_node_attn<<<(N_NODES + 255) / 256, 256, 0, stream>>>(feat, attn_l, attn_r, el, er);

    k_hist  <<<(E_EDGES + 255) / 256, 256, 0, stream>>>(dst, cnt);
    k_alloc <<<(N_NODES + 255) / 256, 256, 0, stream>>>(cnt, startv, cursor, total);
    k_bucket<<<(E_EDGES + 255) / 256, 256, 0, stream>>>(src, dst, cursor, ebuf);
    k_gather<<<(N_NODES * 32 + 255) / 256, 256, 0, stream>>>(startv, cnt, ebuf, el, er,
                                                             feat, bias, xmid);

    k_lstm_mfma<<<(N_NODES + 31) / 32, 256, 0, stream>>>(xmid, h0, Wb_frag, bsum, c0,
                                                         out, out + N_NODES * OUT_DIM,
                                                         out + 2 * N_NODES * OUT_DIM);
}

// Round 6
// 299.150 us; speedup vs baseline: 1.0830x; 1.0830x over previous
//
#include <hip/hip_runtime.h>
#include <math.h>

#define N_NODES 50000
#define E_EDGES 800000
#define IN_DIM  256
#define D_DIM   96
#define OUT_DIM 128

typedef __attribute__((ext_vector_type(8))) short short8;
typedef __attribute__((ext_vector_type(4))) float f32x4;

__device__ __forceinline__ unsigned short f2bf(float f) {
    unsigned u = __float_as_uint(f);
    unsigned r = u + 0x7fffu + ((u >> 16) & 1u);
    return (unsigned short)(r >> 16);
}
__device__ __forceinline__ float bf2f(unsigned short u) {
    return __uint_as_float(((unsigned)u) << 16);
}
__device__ __forceinline__ float sigm(float x) { return 1.f / (1.f + __expf(-x)); }
__device__ __forceinline__ float ftanh(float x) { return 1.f - 2.f / (1.f + __expf(2.f * x)); }

// pack 8 consecutive f32 -> short8 of bf16
__device__ __forceinline__ short8 pack8(const float* __restrict__ p) {
    float4 v0 = *(const float4*)p;
    float4 v1 = *(const float4*)(p + 4);
    union { short8 s; unsigned u[4]; } r;
    r.u[0] = (unsigned)f2bf(v0.x) | ((unsigned)f2bf(v0.y) << 16);
    r.u[1] = (unsigned)f2bf(v0.z) | ((unsigned)f2bf(v0.w) << 16);
    r.u[2] = (unsigned)f2bf(v1.x) | ((unsigned)f2bf(v1.y) << 16);
    r.u[3] = (unsigned)f2bf(v1.z) | ((unsigned)f2bf(v1.w) << 16);
    return r.s;
}

// ---------- K1: feat = x @ W_fc  ([N,256]@[256,96] -> bf16 [N,96]) ----------
__global__ __launch_bounds__(192)
void k_featmm(const float* __restrict__ x, const float* __restrict__ Wfc,
              unsigned short* __restrict__ feat) {
    __shared__ float xs[64][68];
    const int t    = threadIdx.x;
    const int j    = t % 96;
    const int half = t / 96;
    const int n0   = blockIdx.x * 64;
    const int bn   = half * 32;

    float acc[32];
#pragma unroll
    for (int i = 0; i < 32; ++i) acc[i] = 0.f;

    for (int k0 = 0; k0 < IN_DIM; k0 += 64) {
        __syncthreads();
        for (int idx = t; idx < 64 * 64; idx += 192) {
            int nl = idx >> 6, kk = idx & 63;
            int n = n0 + nl;
            xs[kk][nl] = (n < N_NODES) ? x[n * IN_DIM + k0 + kk] : 0.f;
        }
        __syncthreads();
#pragma unroll 4
        for (int kk = 0; kk < 64; ++kk) {
            float w = Wfc[(k0 + kk) * D_DIM + j];
            const float4* row = (const float4*)&xs[kk][bn];
#pragma unroll
            for (int q = 0; q < 8; ++q) {
                float4 v = row[q];
                acc[4*q+0] += w * v.x; acc[4*q+1] += w * v.y;
                acc[4*q+2] += w * v.z; acc[4*q+3] += w * v.w;
            }
        }
    }
#pragma unroll
    for (int i = 0; i < 32; ++i) {
        int n = n0 + bn + i;
        if (n < N_NODES) feat[n * D_DIM + j] = f2bf(acc[i]);
    }
}

// ---------- K2: el/er per node (bf16 feat) ----------
__global__ __launch_bounds__(256)
void k_node_attn(const unsigned short* __restrict__ feat,
                 const float* __restrict__ al, const float* __restrict__ ar,
                 float* __restrict__ el, float* __restrict__ er) {
    int n = blockIdx.x * blockDim.x + threadIdx.x;
    if (n >= N_NODES) return;
    const uint4* f4 = (const uint4*)(feat + n * D_DIM);
    float sl = 0.f, sr = 0.f;
#pragma unroll
    for (int q = 0; q < 12; ++q) {
        uint4 v = f4[q];
        unsigned uu[4] = {v.x, v.y, v.z, v.w};
#pragma unroll
        for (int p = 0; p < 4; ++p) {
            float f0 = bf2f((unsigned short)(uu[p] & 0xffffu));
            float f1 = bf2f((unsigned short)(uu[p] >> 16));
            int k = q * 8 + p * 2;
            sl += f0 * al[k] + f1 * al[k + 1];
            sr += f0 * ar[k] + f1 * ar[k + 1];
        }
    }
    el[n] = sl; er[n] = sr;
}

// ---------- K3a: histogram of dst ----------
__global__ __launch_bounds__(256)
void k_hist(const int* __restrict__ dst, int* __restrict__ cnt) {
    int e = blockIdx.x * blockDim.x + threadIdx.x;
    if (e >= E_EDGES) return;
    atomicAdd(&cnt[dst[e]], 1);
}

// ---------- K3b: wave-parallel range allocator ----------
__global__ __launch_bounds__(256)
void k_alloc(const int* __restrict__ cnt, int* __restrict__ start,
             int* __restrict__ cursor, int* __restrict__ total) {
    const int n    = blockIdx.x * 256 + threadIdx.x;
    const int lane = threadIdx.x & 63;
    int c = (n < N_NODES) ? cnt[n] : 0;
    int incl = c;
#pragma unroll
    for (int d = 1; d < 64; d <<= 1) {
        int v = __shfl_up(incl, d, 64);
        if (lane >= d) incl += v;
    }
    int wsum = __shfl(incl, 63, 64);
    int base = 0;
    if (lane == 63) base = atomicAdd(total, wsum);
    base = __shfl(base, 63, 64);
    if (n < N_NODES) {
        int s = base + incl - c;
        start[n] = s;
        cursor[n] = s;
    }
}

// ---------- K3c: bucket src-ids by dst ----------
__global__ __launch_bounds__(256)
void k_bucket(const int* __restrict__ src, const int* __restrict__ dst,
              int* __restrict__ cursor, int* __restrict__ ebuf_src) {
    int e = blockIdx.x * blockDim.x + threadIdx.x;
    if (e >= E_EDGES) return;
    int pos = atomicAdd(&cursor[dst[e]], 1);
    ebuf_src[pos] = src[e];
}

// ---------- K3d: softmax-gather -> xmid bf16 [N,96] ----------
__global__ __launch_bounds__(256)
void k_gather(const int* __restrict__ start, const int* __restrict__ cnt,
              const int* __restrict__ ebuf_src,
              const float* __restrict__ el, const float* __restrict__ er,
              const unsigned short* __restrict__ feat, const float* __restrict__ bias,
              unsigned short* __restrict__ xmid) {
    const int n    = (blockIdx.x * 256 + threadIdx.x) >> 5;
    const int lane = threadIdx.x & 31;
    if (n >= N_NODES) return;
    const int o0 = start[n];
    const int deg = cnt[n];
    const float ern = er[n];

    float vmax = -INFINITY;
    for (int i = lane; i < deg; i += 32) {
        int s = ebuf_src[o0 + i];
        float v = el[s] + ern; v = v > 0.f ? v : 0.2f * v;
        vmax = fmaxf(vmax, v);
    }
#pragma unroll
    for (int d = 16; d; d >>= 1) vmax = fmaxf(vmax, __shfl_xor(vmax, d, 32));

    float ssum = 0.f;
    for (int i = lane; i < deg; i += 32) {
        int s = ebuf_src[o0 + i];
        float v = el[s] + ern; v = v > 0.f ? v : 0.2f * v;
        ssum += __expf(v - vmax);
    }
#pragma unroll
    for (int d = 16; d; d >>= 1) ssum += __shfl_xor(ssum, d, 32);

    const float inv = 1.f / (ssum > 0.f ? ssum : 1.f);

    float a0 = 0.f, a1 = 0.f, a2 = 0.f;
    for (int i = 0; i < deg; ++i) {
        int s = ebuf_src[o0 + i];
        float v = el[s] + ern; v = v > 0.f ? v : 0.2f * v;
        float w = __expf(v - vmax);
        const unsigned short* fr = feat + s * D_DIM;
        a0 += w * bf2f(fr[lane]);
        a1 += w * bf2f(fr[lane + 32]);
        a2 += w * bf2f(fr[lane + 64]);
    }
    unsigned short* zr = xmid + (size_t)n * D_DIM;
    zr[lane]      = f2bf(ftanh(a0 * inv + bias[lane]));
    zr[lane + 32] = f2bf(ftanh(a1 * inv + bias[lane + 32]));
    zr[lane + 64] = f2bf(ftanh(a2 * inv + bias[lane + 64]));
}

// ---------- prep: h0 f32 -> bf16 ----------
__global__ __launch_bounds__(256)
void k_cast_h0(const float* __restrict__ h0, unsigned short* __restrict__ h0b) {
    int tid = blockIdx.x * 256 + threadIdx.x;
    if (tid >= N_NODES * OUT_DIM / 8) return;
    *(short8*)(h0b + (size_t)tid * 8) = pack8(h0 + (size_t)tid * 8);
}

// ---------- prep: W -> fragment-major packed bf16 + bsum ----------
// Wb_frag[((cf*7+ks)*64+l)*8+j] = W[k][col], k=ks*32+(l>>4)*8+j, col=cf*16+(l&15)
__global__ __launch_bounds__(256)
void k_prep_w(const float* __restrict__ W_ih, const float* __restrict__ W_hh,
              const float* __restrict__ b_ih, const float* __restrict__ b_hh,
              unsigned short* __restrict__ Wb_frag, float* __restrict__ bsum) {
    int tid = blockIdx.x * 256 + threadIdx.x;
    if (tid < 512) bsum[tid] = b_ih[tid] + b_hh[tid];
    if (tid >= 32 * 7 * 64 * 8) return;
    int j = tid & 7;
    int rest = tid >> 3;
    int l = rest & 63;
    int rest2 = rest >> 6;
    int ks = rest2 % 7;
    int cf = rest2 / 7;
    int k   = ks * 32 + (l >> 4) * 8 + j;
    int col = cf * 16 + (l & 15);
    float v = (k < 96) ? W_ih[col * 96 + k] : W_hh[col * 128 + (k - 96)];
    Wb_frag[tid] = f2bf(v);
}

// ---------- K4: transposed-MFMA gates GEMM + LSTM pointwise ----------
// Block: 4 waves, 64 rows. Wave w: output cols [w*32, w*32+32).
// mfma(Wfrag, Zfrag): D[gatecol][node] -> lane holds 4 consecutive gatecols
// (reg dim) for node = lane&15 -> float4 epilogue loads/stores, no LDS.
__global__ __launch_bounds__(256, 2)
void k_lstm_mfma(const unsigned short* __restrict__ xmid,   // [N,96]  bf16
                 const unsigned short* __restrict__ h0b,    // [N,128] bf16
                 const unsigned short* __restrict__ Wb_frag,
                 const float* __restrict__ bsum,
                 const float* __restrict__ cin0,
                 float* __restrict__ out_h1a, float* __restrict__ out_h1b,
                 float* __restrict__ out_c1) {
    const int t     = threadIdx.x;
    const int lane  = t & 63;
    const int w     = t >> 6;
    const int n0    = blockIdx.x * 64;
    const int nfrag = lane & 15;        // node within fragment (D col)
    const int khalf = lane >> 4;        // k-subgroup / D row quarter

    f32x4 acc[4][2][4];                 // [rowfrag][cc][gate]
#pragma unroll
    for (int rf = 0; rf < 4; ++rf)
#pragma unroll
        for (int cc = 0; cc < 2; ++cc)
#pragma unroll
            for (int g = 0; g < 4; ++g)
                acc[rf][cc][g] = (f32x4){0.f, 0.f, 0.f, 0.f};

    const unsigned short* pZ[4];
    const unsigned short* pH[4];
#pragma unroll
    for (int rf = 0; rf < 4; ++rf) {
        int r = min(n0 + rf * 16 + nfrag, N_NODES - 1);   // clamp tail
        pZ[rf] = xmid + (size_t)r * D_DIM + khalf * 8;
        pH[rf] = h0b + (size_t)r * OUT_DIM + khalf * 8;
    }
    const unsigned short* pW = Wb_frag + (size_t)lane * 8;

#pragma unroll 1
    for (int ks = 0; ks < 7; ++ks) {
        short8 zf[4];
        if (ks < 3) {
#pragma unroll
            for (int rf = 0; rf < 4; ++rf)
                zf[rf] = *(const short8*)(pZ[rf] + ks * 32);
        } else {
#pragma unroll
            for (int rf = 0; rf < 4; ++rf)
                zf[rf] = *(const short8*)(pH[rf] + (ks - 3) * 32);
        }
        short8 wf[4][2];
#pragma unroll
        for (int g = 0; g < 4; ++g)
#pragma unroll
            for (int cc = 0; cc < 2; ++cc) {
                int cf = w * 2 + cc + 8 * g;
                wf[g][cc] = *(const short8*)(pW + (size_t)(cf * 7 + ks) * 512);
            }
#pragma unroll
        for (int rf = 0; rf < 4; ++rf)
#pragma unroll
            for (int g = 0; g < 4; ++g)
#pragma unroll
                for (int cc = 0; cc < 2; ++cc)
                    acc[rf][cc][g] = __builtin_amdgcn_mfma_f32_16x16x32_bf16(
                        wf[g][cc], zf[rf], acc[rf][cc][g], 0, 0, 0);
    }

    // epilogue: lane owns 4 consecutive output cols (oc..oc+3) for its node
#pragma unroll
    for (int cc = 0; cc < 2; ++cc) {
        const int oc = (w * 2 + cc) * 16 + khalf * 4;
        const float4 bi = *(const float4*)(bsum + oc);
        const float4 bf = *(const float4*)(bsum + 128 + oc);
        const float4 bg = *(const float4*)(bsum + 256 + oc);
        const float4 bo = *(const float4*)(bsum + 384 + oc);
#pragma unroll
        for (int rf = 0; rf < 4; ++rf) {
            const int node = n0 + rf * 16 + nfrag;
            if (node >= N_NODES) continue;
            const f32x4 I = acc[rf][cc][0];
            const f32x4 F = acc[rf][cc][1];
            const f32x4 G = acc[rf][cc][2];
            const f32x4 O = acc[rf][cc][3];
            const float4 cv = *(const float4*)(cin0 + (size_t)node * OUT_DIM + oc);
            float4 h1, c1;
            c1.x = sigm(F[0] + bf.x) * cv.x + sigm(I[0] + bi.x) * ftanh(G[0] + bg.x);
            c1.y = sigm(F[1] + bf.y) * cv.y + sigm(I[1] + bi.y) * ftanh(G[1] + bg.y);
            c1.z = sigm(F[2] + bf.z) * cv.z + sigm(I[2] + bi.z) * ftanh(G[2] + bg.z);
            c1.w = sigm(F[3] + bf.w) * cv.w + sigm(I[3] + bi.w) * ftanh(G[3] + bg.w);
            h1.x = sigm(O[0] + bo.x) * ftanh(c1.x);
            h1.y = sigm(O[1] + bo.y) * ftanh(c1.y);
            h1.z = sigm(O[2] + bo.z) * ftanh(c1.z);
            h1.w = sigm(O[3] + bo.w) * ftanh(c1.w);
            *(float4*)(out_h1a + (size_t)node * OUT_DIM + oc) = h1;
            *(float4*)(out_h1b + (size_t)node * OUT_DIM + oc) = h1;
            *(float4*)(out_c1  + (size_t)node * OUT_DIM + oc) = c1;
        }
    }
}

extern "C" void kernel_launch(void* const* d_in, const int* in_sizes, int n_in,
                              void* d_out, int out_size, void* d_ws, size_t ws_size,
                              hipStream_t stream) {
    const float* x      = (const float*)d_in[0];
    const float* W_fc   = (const float*)d_in[1];
    const float* attn_l = (const float*)d_in[2];
    const float* attn_r = (const float*)d_in[3];
    const float* bias   = (const float*)d_in[4];
    const float* W_ih   = (const float*)d_in[5];
    const float* W_hh   = (const float*)d_in[6];
    const float* b_ih   = (const float*)d_in[7];
    const float* b_hh   = (const float*)d_in[8];
    const float* h0     = (const float*)d_in[9];
    const float* c0     = (const float*)d_in[10];
    const int*   src    = (const int*)d_in[11];
    const int*   dst    = (const int*)d_in[12];
    float* out = (float*)d_out;

    char* base = (char*)d_ws;
    unsigned short* feat    = (unsigned short*)(base);               //  9,600,000 B
    unsigned short* xmid    = (unsigned short*)(base + 9600000);     //  9,600,000 B
    unsigned short* h0b     = (unsigned short*)(base + 19200000);    // 12,800,000 B
    float*          el      = (float*)(base + 32000000);             //  200,000
    float*          er      = (float*)(base + 32200000);             //  200,000
    int*            cnt     = (int*)(base + 32400000);               //  200,000
    int*            total   = (int*)(base + 32600000);               //  4
    int*            startv  = (int*)(base + 32600004);               //  200,000
    int*            cursor  = (int*)(base + 32800004);               //  200,000
    int*            ebuf    = (int*)(base + 33000004);               //  3,200,000
    unsigned short* Wb_frag = (unsigned short*)(base + 36200016);    //  229,376 (16B aligned)
    float*          bsum    = (float*)(base + 36429392);             //  2,048

    hipMemsetAsync(cnt, 0, (size_t)N_NODES * sizeof(int) + sizeof(int), stream);

    k_prep_w <<<(32 * 7 * 64 * 8 + 255) / 256, 256, 0, stream>>>(W_ih, W_hh, b_ih, b_hh,
                                                                 Wb_frag, bsum);
    k_cast_h0<<<(N_NODES * OUT_DIM / 8 + 255) / 256, 256, 0, stream>>>(h0, h0b);

    k_featmm<<<(N_NODES + 63) / 64, 192, 0, stream>>>(x, W_fc, feat);
    k_node_attn<<<(N_NODES + 255) / 256, 256, 0, stream>>>(feat, attn_l, attn_r, el, er);

    k_hist  <<<(E_EDGES + 255) / 256, 256, 0, stream>>>(dst, cnt);
    k_alloc <<<(N_NODES + 255) / 256, 256, 0, stream>>>(cnt, startv, cursor, total);
    k_bucket<<<(E_EDGES + 255) / 256, 256, 0, stream>>>(src, dst, cursor, ebuf);
    k_gather<<<(N_NODES * 32 + 255) / 256, 256, 0, stream>>>(startv, cnt, ebuf, el, er,
                                                             feat, bias, xmid);

    k_lstm_mfma<<<(N_NODES + 63) / 64, 256, 0, stream>>>(xmid, h0b, Wb_frag, bsum, c0,
                                                         out, out + N_NODES * OUT_DIM,
                                                         out + 2 * N_NODES * OUT_DIM);
}

// Round 7
// 245.138 us; speedup vs baseline: 1.3216x; 1.2203x over previous
//
#include <hip/hip_runtime.h>
#include <math.h>

#define N_NODES 50000
#define E_EDGES 800000
#define IN_DIM  256
#define D_DIM   96
#define OUT_DIM 128

typedef __attribute__((ext_vector_type(8))) short short8;
typedef __attribute__((ext_vector_type(4))) float f32x4;

__device__ __forceinline__ unsigned short f2bf(float f) {
    unsigned u = __float_as_uint(f);
    unsigned r = u + 0x7fffu + ((u >> 16) & 1u);
    return (unsigned short)(r >> 16);
}
__device__ __forceinline__ float bf2f(unsigned short u) {
    return __uint_as_float(((unsigned)u) << 16);
}
__device__ __forceinline__ float sigm(float x) { return 1.f / (1.f + __expf(-x)); }
__device__ __forceinline__ float ftanh(float x) { return 1.f - 2.f / (1.f + __expf(2.f * x)); }

// pack 8 consecutive f32 -> short8 of bf16
__device__ __forceinline__ short8 pack8(const float* __restrict__ p) {
    float4 v0 = *(const float4*)p;
    float4 v1 = *(const float4*)(p + 4);
    union { short8 s; unsigned u[4]; } r;
    r.u[0] = (unsigned)f2bf(v0.x) | ((unsigned)f2bf(v0.y) << 16);
    r.u[1] = (unsigned)f2bf(v0.z) | ((unsigned)f2bf(v0.w) << 16);
    r.u[2] = (unsigned)f2bf(v1.x) | ((unsigned)f2bf(v1.y) << 16);
    r.u[3] = (unsigned)f2bf(v1.z) | ((unsigned)f2bf(v1.w) << 16);
    return r.s;
}

// ---------- prep: W_fc -> fragment-major bf16 ----------
// Wfc_frag[((cf*8+ks)*64+l)*8+j] = W_fc[k][col], k=ks*32+(l>>4)*8+j, col=cf*16+(l&15)
__global__ __launch_bounds__(256)
void k_prep_wfc(const float* __restrict__ Wfc, unsigned short* __restrict__ Wfc_frag) {
    int tid = blockIdx.x * 256 + threadIdx.x;
    if (tid >= 6 * 8 * 64 * 8) return;
    int j = tid & 7;
    int rest = tid >> 3;
    int l = rest & 63;
    int rest2 = rest >> 6;
    int ks = rest2 & 7;
    int cf = rest2 >> 3;
    int k   = ks * 32 + (l >> 4) * 8 + j;
    int col = cf * 16 + (l & 15);
    Wfc_frag[tid] = f2bf(Wfc[k * D_DIM + col]);
}

// ---------- K1: transposed-MFMA feat = x @ W_fc, fused el/er ----------
// Block: 4 waves, 64 nodes. Wave w: nodes [n0+w*16, n0+w*16+16), all 96 cols.
// mfma(Wfrag, Xfrag): lane holds cols oc=cf*16+khalf*4..+3 for node lane&15.
__global__ __launch_bounds__(256, 2)
void k_featmm(const float* __restrict__ x, const unsigned short* __restrict__ Wfc_frag,
              const float* __restrict__ al, const float* __restrict__ ar,
              unsigned short* __restrict__ feat,
              float* __restrict__ el, float* __restrict__ er) {
    const int t     = threadIdx.x;
    const int lane  = t & 63;
    const int w     = t >> 6;
    const int nfrag = lane & 15;
    const int khalf = lane >> 4;
    const int node  = blockIdx.x * 64 + w * 16 + nfrag;
    const int r     = min(node, N_NODES - 1);

    f32x4 acc[6];
#pragma unroll
    for (int cf = 0; cf < 6; ++cf) acc[cf] = (f32x4){0.f, 0.f, 0.f, 0.f};

    const float* px = x + (size_t)r * IN_DIM + khalf * 8;
    const unsigned short* pW = Wfc_frag + (size_t)lane * 8;

#pragma unroll 1
    for (int ks = 0; ks < 8; ++ks) {
        short8 xf = pack8(px + ks * 32);
#pragma unroll
        for (int cf = 0; cf < 6; ++cf) {
            short8 wf = *(const short8*)(pW + (size_t)((cf * 8 + ks) * 64) * 8);
            acc[cf] = __builtin_amdgcn_mfma_f32_16x16x32_bf16(wf, xf, acc[cf], 0, 0, 0);
        }
    }

    // fused el/er: partial dot over this lane's 24 cols, then xor-reduce khalf
    float sl = 0.f, sr = 0.f;
#pragma unroll
    for (int cf = 0; cf < 6; ++cf) {
        const int oc = cf * 16 + khalf * 4;
        const float4 a = *(const float4*)(al + oc);
        const float4 b = *(const float4*)(ar + oc);
        sl += acc[cf][0]*a.x + acc[cf][1]*a.y + acc[cf][2]*a.z + acc[cf][3]*a.w;
        sr += acc[cf][0]*b.x + acc[cf][1]*b.y + acc[cf][2]*b.z + acc[cf][3]*b.w;
    }
    sl += __shfl_xor(sl, 16, 64); sl += __shfl_xor(sl, 32, 64);
    sr += __shfl_xor(sr, 16, 64); sr += __shfl_xor(sr, 32, 64);

    if (node < N_NODES) {
        if (lane < 16) { el[node] = sl; er[node] = sr; }
        // feat store: 4 consecutive bf16 cols per lane (8B)
#pragma unroll
        for (int cf = 0; cf < 6; ++cf) {
            const int oc = cf * 16 + khalf * 4;
            union { unsigned u[2]; } pk;
            pk.u[0] = (unsigned)f2bf(acc[cf][0]) | ((unsigned)f2bf(acc[cf][1]) << 16);
            pk.u[1] = (unsigned)f2bf(acc[cf][2]) | ((unsigned)f2bf(acc[cf][3]) << 16);
            *(uint2*)(feat + (size_t)node * D_DIM + oc) = make_uint2(pk.u[0], pk.u[1]);
        }
    }
}

// ---------- K3a: histogram of dst ----------
__global__ __launch_bounds__(256)
void k_hist(const int* __restrict__ dst, int* __restrict__ cnt) {
    int e = blockIdx.x * blockDim.x + threadIdx.x;
    if (e >= E_EDGES) return;
    atomicAdd(&cnt[dst[e]], 1);
}

// ---------- K3b: wave-parallel range allocator ----------
__global__ __launch_bounds__(256)
void k_alloc(const int* __restrict__ cnt, int* __restrict__ start,
             int* __restrict__ cursor, int* __restrict__ total) {
    const int n    = blockIdx.x * 256 + threadIdx.x;
    const int lane = threadIdx.x & 63;
    int c = (n < N_NODES) ? cnt[n] : 0;
    int incl = c;
#pragma unroll
    for (int d = 1; d < 64; d <<= 1) {
        int v = __shfl_up(incl, d, 64);
        if (lane >= d) incl += v;
    }
    int wsum = __shfl(incl, 63, 64);
    int base = 0;
    if (lane == 63) base = atomicAdd(total, wsum);
    base = __shfl(base, 63, 64);
    if (n < N_NODES) {
        int s = base + incl - c;
        start[n] = s;
        cursor[n] = s;
    }
}

// ---------- K3c: bucket src-ids by dst ----------
__global__ __launch_bounds__(256)
void k_bucket(const int* __restrict__ src, const int* __restrict__ dst,
              int* __restrict__ cursor, int* __restrict__ ebuf_src) {
    int e = blockIdx.x * blockDim.x + threadIdx.x;
    if (e >= E_EDGES) return;
    int pos = atomicAdd(&cursor[dst[e]], 1);
    ebuf_src[pos] = src[e];
}

// ---------- K3d: softmax-gather -> xmid bf16 [N,96] ----------
__global__ __launch_bounds__(256)
void k_gather(const int* __restrict__ start, const int* __restrict__ cnt,
              const int* __restrict__ ebuf_src,
              const float* __restrict__ el, const float* __restrict__ er,
              const unsigned short* __restrict__ feat, const float* __restrict__ bias,
              unsigned short* __restrict__ xmid) {
    const int n    = (blockIdx.x * 256 + threadIdx.x) >> 5;
    const int lane = threadIdx.x & 31;
    if (n >= N_NODES) return;
    const int o0 = start[n];
    const int deg = cnt[n];
    const float ern = er[n];

    float vmax = -INFINITY;
    for (int i = lane; i < deg; i += 32) {
        int s = ebuf_src[o0 + i];
        float v = el[s] + ern; v = v > 0.f ? v : 0.2f * v;
        vmax = fmaxf(vmax, v);
    }
#pragma unroll
    for (int d = 16; d; d >>= 1) vmax = fmaxf(vmax, __shfl_xor(vmax, d, 32));

    float ssum = 0.f;
    for (int i = lane; i < deg; i += 32) {
        int s = ebuf_src[o0 + i];
        float v = el[s] + ern; v = v > 0.f ? v : 0.2f * v;
        ssum += __expf(v - vmax);
    }
#pragma unroll
    for (int d = 16; d; d >>= 1) ssum += __shfl_xor(ssum, d, 32);

    const float inv = 1.f / (ssum > 0.f ? ssum : 1.f);

    float a0 = 0.f, a1 = 0.f, a2 = 0.f;
    for (int i = 0; i < deg; ++i) {
        int s = ebuf_src[o0 + i];
        float v = el[s] + ern; v = v > 0.f ? v : 0.2f * v;
        float w = __expf(v - vmax);
        const unsigned short* fr = feat + s * D_DIM;
        a0 += w * bf2f(fr[lane]);
        a1 += w * bf2f(fr[lane + 32]);
        a2 += w * bf2f(fr[lane + 64]);
    }
    unsigned short* zr = xmid + (size_t)n * D_DIM;
    zr[lane]      = f2bf(ftanh(a0 * inv + bias[lane]));
    zr[lane + 32] = f2bf(ftanh(a1 * inv + bias[lane + 32]));
    zr[lane + 64] = f2bf(ftanh(a2 * inv + bias[lane + 64]));
}

// ---------- prep: h0 f32 -> bf16 ----------
__global__ __launch_bounds__(256)
void k_cast_h0(const float* __restrict__ h0, unsigned short* __restrict__ h0b) {
    int tid = blockIdx.x * 256 + threadIdx.x;
    if (tid >= N_NODES * OUT_DIM / 8) return;
    *(short8*)(h0b + (size_t)tid * 8) = pack8(h0 + (size_t)tid * 8);
}

// ---------- prep: W -> fragment-major packed bf16 + bsum ----------
__global__ __launch_bounds__(256)
void k_prep_w(const float* __restrict__ W_ih, const float* __restrict__ W_hh,
              const float* __restrict__ b_ih, const float* __restrict__ b_hh,
              unsigned short* __restrict__ Wb_frag, float* __restrict__ bsum) {
    int tid = blockIdx.x * 256 + threadIdx.x;
    if (tid < 512) bsum[tid] = b_ih[tid] + b_hh[tid];
    if (tid >= 32 * 7 * 64 * 8) return;
    int j = tid & 7;
    int rest = tid >> 3;
    int l = rest & 63;
    int rest2 = rest >> 6;
    int ks = rest2 % 7;
    int cf = rest2 / 7;
    int k   = ks * 32 + (l >> 4) * 8 + j;
    int col = cf * 16 + (l & 15);
    float v = (k < 96) ? W_ih[col * 96 + k] : W_hh[col * 128 + (k - 96)];
    Wb_frag[tid] = f2bf(v);
}

// ---------- K4: transposed-MFMA gates GEMM + LSTM pointwise ----------
__global__ __launch_bounds__(256, 2)
void k_lstm_mfma(const unsigned short* __restrict__ xmid,   // [N,96]  bf16
                 const unsigned short* __restrict__ h0b,    // [N,128] bf16
                 const unsigned short* __restrict__ Wb_frag,
                 const float* __restrict__ bsum,
                 const float* __restrict__ cin0,
                 float* __restrict__ out_h1a, float* __restrict__ out_h1b,
                 float* __restrict__ out_c1) {
    const int t     = threadIdx.x;
    const int lane  = t & 63;
    const int w     = t >> 6;
    const int n0    = blockIdx.x * 64;
    const int nfrag = lane & 15;
    const int khalf = lane >> 4;

    f32x4 acc[4][2][4];                 // [rowfrag][cc][gate]
#pragma unroll
    for (int rf = 0; rf < 4; ++rf)
#pragma unroll
        for (int cc = 0; cc < 2; ++cc)
#pragma unroll
            for (int g = 0; g < 4; ++g)
                acc[rf][cc][g] = (f32x4){0.f, 0.f, 0.f, 0.f};

    const unsigned short* pZ[4];
    const unsigned short* pH[4];
#pragma unroll
    for (int rf = 0; rf < 4; ++rf) {
        int r = min(n0 + rf * 16 + nfrag, N_NODES - 1);
        pZ[rf] = xmid + (size_t)r * D_DIM + khalf * 8;
        pH[rf] = h0b + (size_t)r * OUT_DIM + khalf * 8;
    }
    const unsigned short* pW = Wb_frag + (size_t)lane * 8;

#pragma unroll 1
    for (int ks = 0; ks < 7; ++ks) {
        short8 zf[4];
        if (ks < 3) {
#pragma unroll
            for (int rf = 0; rf < 4; ++rf)
                zf[rf] = *(const short8*)(pZ[rf] + ks * 32);
        } else {
#pragma unroll
            for (int rf = 0; rf < 4; ++rf)
                zf[rf] = *(const short8*)(pH[rf] + (ks - 3) * 32);
        }
        short8 wf[4][2];
#pragma unroll
        for (int g = 0; g < 4; ++g)
#pragma unroll
            for (int cc = 0; cc < 2; ++cc) {
                int cf = w * 2 + cc + 8 * g;
                wf[g][cc] = *(const short8*)(pW + (size_t)(cf * 7 + ks) * 512);
            }
#pragma unroll
        for (int rf = 0; rf < 4; ++rf)
#pragma unroll
            for (int g = 0; g < 4; ++g)
#pragma unroll
                for (int cc = 0; cc < 2; ++cc)
                    acc[rf][cc][g] = __builtin_amdgcn_mfma_f32_16x16x32_bf16(
                        wf[g][cc], zf[rf], acc[rf][cc][g], 0, 0, 0);
    }

#pragma unroll
    for (int cc = 0; cc < 2; ++cc) {
        const int oc = (w * 2 + cc) * 16 + khalf * 4;
        const float4 bi = *(const float4*)(bsum + oc);
        const float4 bf = *(const float4*)(bsum + 128 + oc);
        const float4 bg = *(const float4*)(bsum + 256 + oc);
        const float4 bo = *(const float4*)(bsum + 384 + oc);
#pragma unroll
        for (int rf = 0; rf < 4; ++rf) {
            const int node = n0 + rf * 16 + nfrag;
            if (node >= N_NODES) continue;
            const f32x4 I = acc[rf][cc][0];
            const f32x4 F = acc[rf][cc][1];
            const f32x4 G = acc[rf][cc][2];
            const f32x4 O = acc[rf][cc][3];
            const float4 cv = *(const float4*)(cin0 + (size_t)node * OUT_DIM + oc);
            float4 h1, c1;
            c1.x = sigm(F[0] + bf.x) * cv.x + sigm(I[0] + bi.x) * ftanh(G[0] + bg.x);
            c1.y = sigm(F[1] + bf.y) * cv.y + sigm(I[1] + bi.y) * ftanh(G[1] + bg.y);
            c1.z = sigm(F[2] + bf.z) * cv.z + sigm(I[2] + bi.z) * ftanh(G[2] + bg.z);
            c1.w = sigm(F[3] + bf.w) * cv.w + sigm(I[3] + bi.w) * ftanh(G[3] + bg.w);
            h1.x = sigm(O[0] + bo.x) * ftanh(c1.x);
            h1.y = sigm(O[1] + bo.y) * ftanh(c1.y);
            h1.z = sigm(O[2] + bo.z) * ftanh(c1.z);
            h1.w = sigm(O[3] + bo.w) * ftanh(c1.w);
            *(float4*)(out_h1a + (size_t)node * OUT_DIM + oc) = h1;
            *(float4*)(out_h1b + (size_t)node * OUT_DIM + oc) = h1;
            *(float4*)(out_c1  + (size_t)node * OUT_DIM + oc) = c1;
        }
    }
}

extern "C" void kernel_launch(void* const* d_in, const int* in_sizes, int n_in,
                              void* d_out, int out_size, void* d_ws, size_t ws_size,
                              hipStream_t stream) {
    const float* x      = (const float*)d_in[0];
    const float* W_fc   = (const float*)d_in[1];
    const float* attn_l = (const float*)d_in[2];
    const float* attn_r = (const float*)d_in[3];
    const float* bias   = (const float*)d_in[4];
    const float* W_ih   = (const float*)d_in[5];
    const float* W_hh   = (const float*)d_in[6];
    const float* b_ih   = (const float*)d_in[7];
    const float* b_hh   = (const float*)d_in[8];
    const float* h0     = (const float*)d_in[9];
    const float* c0     = (const float*)d_in[10];
    const int*   src    = (const int*)d_in[11];
    const int*   dst    = (const int*)d_in[12];
    float* out = (float*)d_out;

    char* base = (char*)d_ws;
    unsigned short* feat     = (unsigned short*)(base);               //  9,600,000 B
    unsigned short* xmid     = (unsigned short*)(base + 9600000);     //  9,600,000 B
    unsigned short* h0b      = (unsigned short*)(base + 19200000);    // 12,800,000 B
    float*          el       = (float*)(base + 32000000);             //  200,000
    float*          er       = (float*)(base + 32200000);             //  200,000
    int*            cnt      = (int*)(base + 32400000);               //  200,000
    int*            total    = (int*)(base + 32600000);               //  4
    int*            startv   = (int*)(base + 32600004);               //  200,000
    int*            cursor   = (int*)(base + 32800004);               //  200,000
    int*            ebuf     = (int*)(base + 33000004);               //  3,200,000
    unsigned short* Wb_frag  = (unsigned short*)(base + 36200016);    //  229,376
    float*          bsum     = (float*)(base + 36429392);             //  2,048
    unsigned short* Wfc_frag = (unsigned short*)(base + 36431440);    //  49,152

    hipMemsetAsync(cnt, 0, (size_t)N_NODES * sizeof(int) + sizeof(int), stream);

    k_prep_w  <<<(32 * 7 * 64 * 8 + 255) / 256, 256, 0, stream>>>(W_ih, W_hh, b_ih, b_hh,
                                                                  Wb_frag, bsum);
    k_prep_wfc<<<(6 * 8 * 64 * 8 + 255) / 256, 256, 0, stream>>>(W_fc, Wfc_frag);
    k_cast_h0 <<<(N_NODES * OUT_DIM / 8 + 255) / 256, 256, 0, stream>>>(h0, h0b);

    k_featmm<<<(N_NODES + 63) / 64, 256, 0, stream>>>(x, Wfc_frag, attn_l, attn_r,
                                                      feat, el, er);

    k_hist  <<<(E_EDGES + 255) / 256, 256, 0, stream>>>(dst, cnt);
    k_alloc <<<(N_NODES + 255) / 256, 256, 0, stream>>>(cnt, startv, cursor, total);
    k_bucket<<<(E_EDGES + 255) / 256, 256, 0, stream>>>(src, dst, cursor, ebuf);
    k_gather<<<(N_NODES * 32 + 255) / 256, 256, 0, stream>>>(startv, cnt, ebuf, el, er,
                                                             feat, bias, xmid);

    k_lstm_mfma<<<(N_NODES + 63) / 64, 256, 0, stream>>>(xmid, h0b, Wb_frag, bsum, c0,
                                                         out, out + N_NODES * OUT_DIM,
                                                         out + 2 * N_NODES * OUT_DIM);
}

// Round 8
// 222.473 us; speedup vs baseline: 1.4563x; 1.1019x over previous
//
#include <hip/hip_runtime.h>
#include <math.h>

#define N_NODES 50000
#define E_EDGES 800000
#define IN_DIM  256
#define D_DIM   96
#define OUT_DIM 128

typedef __attribute__((ext_vector_type(8))) short short8;
typedef __attribute__((ext_vector_type(4))) float f32x4;

__device__ __forceinline__ unsigned short f2bf(float f) {
    unsigned u = __float_as_uint(f);
    unsigned r = u + 0x7fffu + ((u >> 16) & 1u);
    return (unsigned short)(r >> 16);
}
__device__ __forceinline__ float bf2f(unsigned short u) {
    return __uint_as_float(((unsigned)u) << 16);
}
__device__ __forceinline__ float sigm(float x) { return 1.f / (1.f + __expf(-x)); }
__device__ __forceinline__ float ftanh(float x) { return 1.f - 2.f / (1.f + __expf(2.f * x)); }

// pack 8 consecutive f32 -> short8 of bf16
__device__ __forceinline__ short8 pack8(const float* __restrict__ p) {
    float4 v0 = *(const float4*)p;
    float4 v1 = *(const float4*)(p + 4);
    union { short8 s; unsigned u[4]; } r;
    r.u[0] = (unsigned)f2bf(v0.x) | ((unsigned)f2bf(v0.y) << 16);
    r.u[1] = (unsigned)f2bf(v0.z) | ((unsigned)f2bf(v0.w) << 16);
    r.u[2] = (unsigned)f2bf(v1.x) | ((unsigned)f2bf(v1.y) << 16);
    r.u[3] = (unsigned)f2bf(v1.z) | ((unsigned)f2bf(v1.w) << 16);
    return r.s;
}

// ---------- prep: W_fc -> fragment-major bf16 ----------
__global__ __launch_bounds__(256)
void k_prep_wfc(const float* __restrict__ Wfc, unsigned short* __restrict__ Wfc_frag) {
    int tid = blockIdx.x * 256 + threadIdx.x;
    if (tid >= 6 * 8 * 64 * 8) return;
    int j = tid & 7;
    int rest = tid >> 3;
    int l = rest & 63;
    int rest2 = rest >> 6;
    int ks = rest2 & 7;
    int cf = rest2 >> 3;
    int k   = ks * 32 + (l >> 4) * 8 + j;
    int col = cf * 16 + (l & 15);
    Wfc_frag[tid] = f2bf(Wfc[k * D_DIM + col]);
}

// ---------- K1: transposed-MFMA feat = x @ W_fc, fused el/er ----------
__global__ __launch_bounds__(256, 2)
void k_featmm(const float* __restrict__ x, const unsigned short* __restrict__ Wfc_frag,
              const float* __restrict__ al, const float* __restrict__ ar,
              unsigned short* __restrict__ feat,
              float* __restrict__ el, float* __restrict__ er) {
    const int t     = threadIdx.x;
    const int lane  = t & 63;
    const int w     = t >> 6;
    const int nfrag = lane & 15;
    const int khalf = lane >> 4;
    const int node  = blockIdx.x * 64 + w * 16 + nfrag;
    const int r     = min(node, N_NODES - 1);

    f32x4 acc[6];
#pragma unroll
    for (int cf = 0; cf < 6; ++cf) acc[cf] = (f32x4){0.f, 0.f, 0.f, 0.f};

    const float* px = x + (size_t)r * IN_DIM + khalf * 8;
    const unsigned short* pW = Wfc_frag + (size_t)lane * 8;

#pragma unroll 1
    for (int ks = 0; ks < 8; ++ks) {
        short8 xf = pack8(px + ks * 32);
#pragma unroll
        for (int cf = 0; cf < 6; ++cf) {
            short8 wf = *(const short8*)(pW + (size_t)((cf * 8 + ks) * 64) * 8);
            acc[cf] = __builtin_amdgcn_mfma_f32_16x16x32_bf16(wf, xf, acc[cf], 0, 0, 0);
        }
    }

    float sl = 0.f, sr = 0.f;
#pragma unroll
    for (int cf = 0; cf < 6; ++cf) {
        const int oc = cf * 16 + khalf * 4;
        const float4 a = *(const float4*)(al + oc);
        const float4 b = *(const float4*)(ar + oc);
        sl += acc[cf][0]*a.x + acc[cf][1]*a.y + acc[cf][2]*a.z + acc[cf][3]*a.w;
        sr += acc[cf][0]*b.x + acc[cf][1]*b.y + acc[cf][2]*b.z + acc[cf][3]*b.w;
    }
    sl += __shfl_xor(sl, 16, 64); sl += __shfl_xor(sl, 32, 64);
    sr += __shfl_xor(sr, 16, 64); sr += __shfl_xor(sr, 32, 64);

    if (node < N_NODES) {
        if (lane < 16) { el[node] = sl; er[node] = sr; }
#pragma unroll
        for (int cf = 0; cf < 6; ++cf) {
            const int oc = cf * 16 + khalf * 4;
            union { unsigned u[2]; } pk;
            pk.u[0] = (unsigned)f2bf(acc[cf][0]) | ((unsigned)f2bf(acc[cf][1]) << 16);
            pk.u[1] = (unsigned)f2bf(acc[cf][2]) | ((unsigned)f2bf(acc[cf][3]) << 16);
            *(uint2*)(feat + (size_t)node * D_DIM + oc) = make_uint2(pk.u[0], pk.u[1]);
        }
    }
}

// ---------- K3a: histogram of dst ----------
__global__ __launch_bounds__(256)
void k_hist(const int* __restrict__ dst, int* __restrict__ cnt) {
    int e = blockIdx.x * blockDim.x + threadIdx.x;
    if (e >= E_EDGES) return;
    atomicAdd(&cnt[dst[e]], 1);
}

// ---------- K3b: wave-parallel range allocator ----------
__global__ __launch_bounds__(256)
void k_alloc(const int* __restrict__ cnt, int* __restrict__ start,
             int* __restrict__ cursor, int* __restrict__ total) {
    const int n    = blockIdx.x * 256 + threadIdx.x;
    const int lane = threadIdx.x & 63;
    int c = (n < N_NODES) ? cnt[n] : 0;
    int incl = c;
#pragma unroll
    for (int d = 1; d < 64; d <<= 1) {
        int v = __shfl_up(incl, d, 64);
        if (lane >= d) incl += v;
    }
    int wsum = __shfl(incl, 63, 64);
    int base = 0;
    if (lane == 63) base = atomicAdd(total, wsum);
    base = __shfl(base, 63, 64);
    if (n < N_NODES) {
        int s = base + incl - c;
        start[n] = s;
        cursor[n] = s;
    }
}

// ---------- K3c: bucket src-ids by dst ----------
__global__ __launch_bounds__(256)
void k_bucket(const int* __restrict__ src, const int* __restrict__ dst,
              int* __restrict__ cursor, int* __restrict__ ebuf_src) {
    int e = blockIdx.x * blockDim.x + threadIdx.x;
    if (e >= E_EDGES) return;
    int pos = atomicAdd(&cursor[dst[e]], 1);
    ebuf_src[pos] = src[e];
}

// ---------- K3d: softmax-gather -> xmid bf16 [N,96] ----------
// Fast path deg<=32: edge ids + softmax weights cached in registers,
// broadcast via shfl in the gather loop (one pass over ebuf/el, one expf/edge).
__global__ __launch_bounds__(256)
void k_gather(const int* __restrict__ start, const int* __restrict__ cnt,
              const int* __restrict__ ebuf_src,
              const float* __restrict__ el, const float* __restrict__ er,
              const unsigned short* __restrict__ feat, const float* __restrict__ bias,
              unsigned short* __restrict__ xmid) {
    const int n    = (blockIdx.x * 256 + threadIdx.x) >> 5;
    const int lane = threadIdx.x & 31;
    if (n >= N_NODES) return;
    const int o0 = start[n];
    const int deg = cnt[n];
    const float ern = er[n];

    float a0 = 0.f, a1 = 0.f, a2 = 0.f;
    float inv;

    if (deg <= 32) {
        int   s_l = 0;
        float v_l = -INFINITY;
        if (lane < deg) {
            s_l = ebuf_src[o0 + lane];
            float v = el[s_l] + ern; v_l = v > 0.f ? v : 0.2f * v;
        }
        float vmax = v_l;
#pragma unroll
        for (int d = 16; d; d >>= 1) vmax = fmaxf(vmax, __shfl_xor(vmax, d, 32));
        float w_l = (lane < deg) ? __expf(v_l - vmax) : 0.f;
        float ssum = w_l;
#pragma unroll
        for (int d = 16; d; d >>= 1) ssum += __shfl_xor(ssum, d, 32);
        inv = 1.f / (ssum > 0.f ? ssum : 1.f);

        for (int i = 0; i < deg; ++i) {
            int   s = __shfl(s_l, i, 32);
            float w = __shfl(w_l, i, 32);
            const unsigned short* fr = feat + (size_t)s * D_DIM;
            a0 += w * bf2f(fr[lane]);
            a1 += w * bf2f(fr[lane + 32]);
            a2 += w * bf2f(fr[lane + 64]);
        }
    } else {
        float vmax = -INFINITY;
        for (int i = lane; i < deg; i += 32) {
            int s = ebuf_src[o0 + i];
            float v = el[s] + ern; v = v > 0.f ? v : 0.2f * v;
            vmax = fmaxf(vmax, v);
        }
#pragma unroll
        for (int d = 16; d; d >>= 1) vmax = fmaxf(vmax, __shfl_xor(vmax, d, 32));

        float ssum = 0.f;
        for (int i = lane; i < deg; i += 32) {
            int s = ebuf_src[o0 + i];
            float v = el[s] + ern; v = v > 0.f ? v : 0.2f * v;
            ssum += __expf(v - vmax);
        }
#pragma unroll
        for (int d = 16; d; d >>= 1) ssum += __shfl_xor(ssum, d, 32);
        inv = 1.f / (ssum > 0.f ? ssum : 1.f);

        for (int bi0 = 0; bi0 < deg; bi0 += 32) {
            int   i_l = bi0 + lane;
            int   s_l = 0; float w_l = 0.f;
            if (i_l < deg) {
                s_l = ebuf_src[o0 + i_l];
                float v = el[s_l] + ern; v = v > 0.f ? v : 0.2f * v;
                w_l = __expf(v - vmax);
            }
            int m = min(32, deg - bi0);
            for (int i = 0; i < m; ++i) {
                int   s = __shfl(s_l, i, 32);
                float w = __shfl(w_l, i, 32);
                const unsigned short* fr = feat + (size_t)s * D_DIM;
                a0 += w * bf2f(fr[lane]);
                a1 += w * bf2f(fr[lane + 32]);
                a2 += w * bf2f(fr[lane + 64]);
            }
        }
    }

    unsigned short* zr = xmid + (size_t)n * D_DIM;
    zr[lane]      = f2bf(ftanh(a0 * inv + bias[lane]));
    zr[lane + 32] = f2bf(ftanh(a1 * inv + bias[lane + 32]));
    zr[lane + 64] = f2bf(ftanh(a2 * inv + bias[lane + 64]));
}

// ---------- prep: h0 f32 -> bf16 ----------
__global__ __launch_bounds__(256)
void k_cast_h0(const float* __restrict__ h0, unsigned short* __restrict__ h0b) {
    int tid = blockIdx.x * 256 + threadIdx.x;
    if (tid >= N_NODES * OUT_DIM / 8) return;
    *(short8*)(h0b + (size_t)tid * 8) = pack8(h0 + (size_t)tid * 8);
}

// ---------- prep: W -> fragment-major packed bf16 + bsum ----------
__global__ __launch_bounds__(256)
void k_prep_w(const float* __restrict__ W_ih, const float* __restrict__ W_hh,
              const float* __restrict__ b_ih, const float* __restrict__ b_hh,
              unsigned short* __restrict__ Wb_frag, float* __restrict__ bsum) {
    int tid = blockIdx.x * 256 + threadIdx.x;
    if (tid < 512) bsum[tid] = b_ih[tid] + b_hh[tid];
    if (tid >= 32 * 7 * 64 * 8) return;
    int j = tid & 7;
    int rest = tid >> 3;
    int l = rest & 63;
    int rest2 = rest >> 6;
    int ks = rest2 % 7;
    int cf = rest2 / 7;
    int k   = ks * 32 + (l >> 4) * 8 + j;
    int col = cf * 16 + (l & 15);
    float v = (k < 96) ? W_ih[col * 96 + k] : W_hh[col * 128 + (k - 96)];
    Wb_frag[tid] = f2bf(v);
}

// ---------- K4: transposed-MFMA gates GEMM, register double-buffered K-loop ----------
#define LOADZ(buf, KS) do {                                                        \
    if ((KS) < 3) {                                                                \
        _Pragma("unroll")                                                          \
        for (int rf_ = 0; rf_ < 4; ++rf_)                                          \
            buf[rf_] = *(const short8*)(pZ[rf_] + (KS) * 32);                      \
    } else {                                                                       \
        _Pragma("unroll")                                                          \
        for (int rf_ = 0; rf_ < 4; ++rf_)                                          \
            buf[rf_] = *(const short8*)(pH[rf_] + ((KS) - 3) * 32);                \
    }                                                                              \
} while (0)

#define LOADW(buf, KS) do {                                                        \
    _Pragma("unroll")                                                              \
    for (int g_ = 0; g_ < 4; ++g_)                                                 \
        _Pragma("unroll")                                                          \
        for (int cc_ = 0; cc_ < 2; ++cc_) {                                        \
            int cf_ = w * 2 + cc_ + 8 * g_;                                        \
            buf[g_][cc_] = *(const short8*)(pW + (size_t)(cf_ * 7 + (KS)) * 512);  \
        }                                                                          \
} while (0)

__global__ __launch_bounds__(256, 2)
void k_lstm_mfma(const unsigned short* __restrict__ xmid,   // [N,96]  bf16
                 const unsigned short* __restrict__ h0b,    // [N,128] bf16
                 const unsigned short* __restrict__ Wb_frag,
                 const float* __restrict__ bsum,
                 const float* __restrict__ cin0,
                 float* __restrict__ out_h1a, float* __restrict__ out_h1b,
                 float* __restrict__ out_c1) {
    const int t     = threadIdx.x;
    const int lane  = t & 63;
    const int w     = t >> 6;
    const int n0    = blockIdx.x * 64;
    const int nfrag = lane & 15;
    const int khalf = lane >> 4;

    f32x4 acc[4][2][4];                 // [rowfrag][cc][gate]
#pragma unroll
    for (int rf = 0; rf < 4; ++rf)
#pragma unroll
        for (int cc = 0; cc < 2; ++cc)
#pragma unroll
            for (int g = 0; g < 4; ++g)
                acc[rf][cc][g] = (f32x4){0.f, 0.f, 0.f, 0.f};

    const unsigned short* pZ[4];
    const unsigned short* pH[4];
#pragma unroll
    for (int rf = 0; rf < 4; ++rf) {
        int r = min(n0 + rf * 16 + nfrag, N_NODES - 1);
        pZ[rf] = xmid + (size_t)r * D_DIM + khalf * 8;
        pH[rf] = h0b + (size_t)r * OUT_DIM + khalf * 8;
    }
    const unsigned short* pW = Wb_frag + (size_t)lane * 8;

    short8 zbuf[2][4];
    short8 wbuf[2][4][2];
    LOADZ(zbuf[0], 0);
    LOADW(wbuf[0], 0);

#pragma unroll
    for (int ks = 0; ks < 7; ++ks) {
        const int cur = ks & 1, nxt = cur ^ 1;
        if (ks < 6) {                       // prefetch ks+1 before consuming ks
            LOADZ(zbuf[nxt], ks + 1);
            LOADW(wbuf[nxt], ks + 1);
        }
#pragma unroll
        for (int rf = 0; rf < 4; ++rf)
#pragma unroll
            for (int g = 0; g < 4; ++g)
#pragma unroll
                for (int cc = 0; cc < 2; ++cc)
                    acc[rf][cc][g] = __builtin_amdgcn_mfma_f32_16x16x32_bf16(
                        wbuf[cur][g][cc], zbuf[cur][rf], acc[rf][cc][g], 0, 0, 0);
    }

#pragma unroll
    for (int cc = 0; cc < 2; ++cc) {
        const int oc = (w * 2 + cc) * 16 + khalf * 4;
        const float4 bi = *(const float4*)(bsum + oc);
        const float4 bf = *(const float4*)(bsum + 128 + oc);
        const float4 bg = *(const float4*)(bsum + 256 + oc);
        const float4 bo = *(const float4*)(bsum + 384 + oc);
#pragma unroll
        for (int rf = 0; rf < 4; ++rf) {
            const int node = n0 + rf * 16 + nfrag;
            if (node >= N_NODES) continue;
            const f32x4 I = acc[rf][cc][0];
            const f32x4 F = acc[rf][cc][1];
            const f32x4 G = acc[rf][cc][2];
            const f32x4 O = acc[rf][cc][3];
            const float4 cv = *(const float4*)(cin0 + (size_t)node * OUT_DIM + oc);
            float4 h1, c1;
            c1.x = sigm(F[0] + bf.x) * cv.x + sigm(I[0] + bi.x) * ftanh(G[0] + bg.x);
            c1.y = sigm(F[1] + bf.y) * cv.y + sigm(I[1] + bi.y) * ftanh(G[1] + bg.y);
            c1.z = sigm(F[2] + bf.z) * cv.z + sigm(I[2] + bi.z) * ftanh(G[2] + bg.z);
            c1.w = sigm(F[3] + bf.w) * cv.w + sigm(I[3] + bi.w) * ftanh(G[3] + bg.w);
            h1.x = sigm(O[0] + bo.x) * ftanh(c1.x);
            h1.y = sigm(O[1] + bo.y) * ftanh(c1.y);
            h1.z = sigm(O[2] + bo.z) * ftanh(c1.z);
            h1.w = sigm(O[3] + bo.w) * ftanh(c1.w);
            *(float4*)(out_h1a + (size_t)node * OUT_DIM + oc) = h1;
            *(float4*)(out_h1b + (size_t)node * OUT_DIM + oc) = h1;
            *(float4*)(out_c1  + (size_t)node * OUT_DIM + oc) = c1;
        }
    }
}

extern "C" void kernel_launch(void* const* d_in, const int* in_sizes, int n_in,
                              void* d_out, int out_size, void* d_ws, size_t ws_size,
                              hipStream_t stream) {
    const float* x      = (const float*)d_in[0];
    const float* W_fc   = (const float*)d_in[1];
    const float* attn_l = (const float*)d_in[2];
    const float* attn_r = (const float*)d_in[3];
    const float* bias   = (const float*)d_in[4];
    const float* W_ih   = (const float*)d_in[5];
    const float* W_hh   = (const float*)d_in[6];
    const float* b_ih   = (const float*)d_in[7];
    const float* b_hh   = (const float*)d_in[8];
    const float* h0     = (const float*)d_in[9];
    const float* c0     = (const float*)d_in[10];
    const int*   src    = (const int*)d_in[11];
    const int*   dst    = (const int*)d_in[12];
    float* out = (float*)d_out;

    char* base = (char*)d_ws;
    unsigned short* feat     = (unsigned short*)(base);               //  9,600,000 B
    unsigned short* xmid     = (unsigned short*)(base + 9600000);     //  9,600,000 B
    unsigned short* h0b      = (unsigned short*)(base + 19200000);    // 12,800,000 B
    float*          el       = (float*)(base + 32000000);             //  200,000
    float*          er       = (float*)(base + 32200000);             //  200,000
    int*            cnt      = (int*)(base + 32400000);               //  200,000
    int*            total    = (int*)(base + 32600000);               //  4
    int*            startv   = (int*)(base + 32600004);               //  200,000
    int*            cursor   = (int*)(base + 32800004);               //  200,000
    int*            ebuf     = (int*)(base + 33000004);               //  3,200,000
    unsigned short* Wb_frag  = (unsigned short*)(base + 36200016);    //  229,376
    float*          bsum     = (float*)(base + 36429392);             //  2,048
    unsigned short* Wfc_frag = (unsigned short*)(base + 36431440);    //  49,152

    hipMemsetAsync(cnt, 0, (size_t)N_NODES * sizeof(int) + sizeof(int), stream);

    k_prep_w  <<<(32 * 7 * 64 * 8 + 255) / 256, 256, 0, stream>>>(W_ih, W_hh, b_ih, b_hh,
                                                                  Wb_frag, bsum);
    k_prep_wfc<<<(6 * 8 * 64 * 8 + 255) / 256, 256, 0, stream>>>(W_fc, Wfc_frag);
    k_cast_h0 <<<(N_NODES * OUT_DIM / 8 + 255) / 256, 256, 0, stream>>>(h0, h0b);

    k_featmm<<<(N_NODES + 63) / 64, 256, 0, stream>>>(x, Wfc_frag, attn_l, attn_r,
                                                      feat, el, er);

    k_hist  <<<(E_EDGES + 255) / 256, 256, 0, stream>>>(dst, cnt);
    k_alloc <<<(N_NODES + 255) / 256, 256, 0, stream>>>(cnt, startv, cursor, total);
    k_bucket<<<(E_EDGES + 255) / 256, 256, 0, stream>>>(src, dst, cursor, ebuf);
    k_gather<<<(N_NODES * 32 + 255) / 256, 256, 0, stream>>>(startv, cnt, ebuf, el, er,
                                                             feat, bias, xmid);

    k_lstm_mfma<<<(N_NODES + 63) / 64, 256, 0, stream>>>(xmid, h0b, Wb_frag, bsum, c0,
                                                         out, out + N_NODES * OUT_DIM,
                                                         out + 2 * N_NODES * OUT_DIM);
}